// Round 1
// baseline (206.308 us; speedup 1.0000x reference)
//
#include <hip/hip_runtime.h>
#include <stdint.h>

// SimpleGPT2Attention on MI355X (gfx950).
// B=2, S=2048, D=1024, H=16, dh=64. All inputs f32; output f32.
// Pipeline: cast->f16, transpose weights, QKV GEMM (f16 MFMA), flash attn, out GEMM.

typedef _Float16 f16;
typedef __attribute__((ext_vector_type(8))) _Float16 f16x8;
typedef __attribute__((ext_vector_type(4))) _Float16 f16x4;
typedef __attribute__((ext_vector_type(4))) float f32x4;

#define NB 2
#define SEQ 2048
#define DMODEL 1024
#define NH 16
#define DH 64

// async global->LDS, 16B per lane, dst = wave-uniform base + lane*16 (HW rule)
__device__ __forceinline__ void gload_lds16(const void* g, void* l) {
  __builtin_amdgcn_global_load_lds(
      (const __attribute__((address_space(1))) unsigned int*)g,
      (__attribute__((address_space(3))) unsigned int*)l, 16, 0, 0);
}

// ---------------- cast f32 -> f16, 8 elems/thread ----------------
__global__ __launch_bounds__(256) void cast_f16_3(
    const float* __restrict__ s0, const float* __restrict__ s1,
    const float* __restrict__ s2, f16* __restrict__ d0, f16* __restrict__ d1,
    f16* __restrict__ d2) {
  const float* src = blockIdx.z == 0 ? s0 : (blockIdx.z == 1 ? s1 : s2);
  f16* dst = blockIdx.z == 0 ? d0 : (blockIdx.z == 1 ? d1 : d2);
  int i = (blockIdx.x * 256 + threadIdx.x) * 8;
  float4 a = *(const float4*)(src + i);
  float4 b = *(const float4*)(src + i + 4);
  f16x8 o;
  o[0] = (f16)a.x; o[1] = (f16)a.y; o[2] = (f16)a.z; o[3] = (f16)a.w;
  o[4] = (f16)b.x; o[5] = (f16)b.y; o[6] = (f16)b.z; o[7] = (f16)b.w;
  *(f16x8*)(dst + i) = o;
}

// ---------------- W [K][N] f32 -> WT [N][K] f16 ----------------
__global__ __launch_bounds__(256) void transw(
    const float* __restrict__ w0, const float* __restrict__ w1,
    const float* __restrict__ w2, const float* __restrict__ w3,
    f16* __restrict__ t0, f16* __restrict__ t1, f16* __restrict__ t2,
    f16* __restrict__ t3) {
  __shared__ float tile[64][65];
  const float* W; f16* T;
  switch (blockIdx.z) {
    case 0: W = w0; T = t0; break;
    case 1: W = w1; T = t1; break;
    case 2: W = w2; T = t2; break;
    default: W = w3; T = t3; break;
  }
  int r0 = blockIdx.y * 64, c0 = blockIdx.x * 64;
  for (int it = 0; it < 16; ++it) {
    int idx = it * 256 + threadIdx.x;
    int r = idx >> 6, c = idx & 63;
    tile[r][c] = W[(size_t)(r0 + r) * DMODEL + c0 + c];
  }
  __syncthreads();
  for (int it = 0; it < 16; ++it) {
    int idx = it * 256 + threadIdx.x;
    int r = idx >> 6, c = idx & 63;
    T[(size_t)(c0 + r) * DMODEL + r0 + c] = (f16)tile[c][r];
  }
}

// ---------------- GEMM: C[m][n] = A[m][:] . BT[n][:] + bias[n] ----------------
// 128x128 tile, BK=64, 4 waves (2x2 of 64x64), mfma_f32_16x16x32_f16.
// LDS tiles [128 rows][64 k] f16, 16B-chunk XOR swizzle (chunk ^= row&7),
// achieved via pre-swizzled global source + swizzled ds_read (LDS linear).
// mode 0: Q out (scaled 0.125, [BH,S,64] f16)   mode 1: K out ([BH,S,64] f16)
// mode 2: V out transposed ([BH,64,S] f16)      mode 3: f32 out (d_out)
__global__ __launch_bounds__(256) void gemm128(
    const f16* __restrict__ xq, const f16* __restrict__ xk,
    const f16* __restrict__ xv, const f16* __restrict__ ao,
    const f16* __restrict__ wqt, const f16* __restrict__ wkt,
    const f16* __restrict__ wvt, const f16* __restrict__ wpt,
    const float* __restrict__ bq, const float* __restrict__ bk,
    const float* __restrict__ bv, const float* __restrict__ bp,
    f16* __restrict__ qo, f16* __restrict__ ko, f16* __restrict__ vto,
    float* __restrict__ out, int mode_base) {
  __shared__ char lds[32768];
  char* ldsA = lds;
  char* ldsB = lds + 16384;

  int mode = mode_base + blockIdx.z;
  const f16* Am; const f16* Bt; const float* bias; float oscale = 1.0f;
  if (mode == 0)      { Am = xq; Bt = wqt; bias = bq; oscale = 0.125f; }
  else if (mode == 1) { Am = xk; Bt = wkt; bias = bk; }
  else if (mode == 2) { Am = xv; Bt = wvt; bias = bv; }
  else                { Am = ao; Bt = wpt; bias = bp; }

  const int tid = threadIdx.x;
  const int l = tid & 63, w = tid >> 6;
  const int g = l >> 4, c = l & 15;
  const int wr = w >> 1, wc = w & 1;
  const int m0 = blockIdx.y * 128, n0 = blockIdx.x * 128;

  // staging: LDS byte p = it*4096 + w*1024 + lane*16
  // row = it*32 + w*8 + (l>>3); stored chunk slot = l&7; logical = slot ^ (row&7)
  const int srow = w * 8 + (l >> 3);
  const int schunk = (l & 7) ^ ((l >> 3) & 7);

  f32x4 acc[4][4] = {};

  for (int k0 = 0; k0 < DMODEL; k0 += 64) {
#pragma unroll
    for (int it = 0; it < 4; ++it) {
      int row = it * 32 + srow;
      gload_lds16(Am + (size_t)(m0 + row) * DMODEL + k0 + schunk * 8,
                  ldsA + it * 4096 + w * 1024);
    }
#pragma unroll
    for (int it = 0; it < 4; ++it) {
      int row = it * 32 + srow;
      gload_lds16(Bt + (size_t)(n0 + row) * DMODEL + k0 + schunk * 8,
                  ldsB + it * 4096 + w * 1024);
    }
    __syncthreads();
    f16x8 af[2][4], bf[2][4];
#pragma unroll
    for (int kc = 0; kc < 2; ++kc)
#pragma unroll
      for (int i = 0; i < 4; ++i) {
        int row = wr * 64 + i * 16 + c;
        af[kc][i] = *(const f16x8*)(ldsA + row * 128 + (((kc * 4 + g) ^ (row & 7)) << 4));
        int rowb = wc * 64 + i * 16 + c;
        bf[kc][i] = *(const f16x8*)(ldsB + rowb * 128 + (((kc * 4 + g) ^ (rowb & 7)) << 4));
      }
#pragma unroll
    for (int kc = 0; kc < 2; ++kc)
#pragma unroll
      for (int i = 0; i < 4; ++i)
#pragma unroll
        for (int j = 0; j < 4; ++j)
          acc[i][j] = __builtin_amdgcn_mfma_f32_16x16x32_f16(af[kc][i], bf[kc][j],
                                                             acc[i][j], 0, 0, 0);
    __syncthreads();
  }

  // epilogue: lane holds C[(l>>4)*4 + e][l&15] per 16x16 frag (m89 layout)
#pragma unroll
  for (int i = 0; i < 4; ++i) {
#pragma unroll
    for (int j = 0; j < 4; ++j) {
      int grb = m0 + wr * 64 + i * 16 + g * 4;
      int gc = n0 + wc * 64 + j * 16 + c;
      float bval = bias[gc];
      if (mode == 3) {
#pragma unroll
        for (int e = 0; e < 4; ++e)
          out[(size_t)(grb + e) * DMODEL + gc] = acc[i][j][e] + bval;
      } else if (mode == 2) {  // V^T: [BH][dh][S]
        int b = grb >> 11, s = grb & 2047, h = gc >> 6, d = gc & 63;
        f16x4 pk;
#pragma unroll
        for (int e = 0; e < 4; ++e) pk[e] = (f16)(acc[i][j][e] + bval);
        *(f16x4*)(vto + ((size_t)((b * NH + h) * DH + d)) * SEQ + s) = pk;
      } else {  // Q/K: [BH][S][dh]
        f16* dst = (mode == 0) ? qo : ko;
        int b = grb >> 11, s = grb & 2047, h = gc >> 6, d = gc & 63;
#pragma unroll
        for (int e = 0; e < 4; ++e)
          dst[(((size_t)(b * NH + h) * SEQ) + (s + e)) * DH + d] =
              (f16)((acc[i][j][e] + bval) * oscale);
      }
    }
  }
}

// ---------------- flash attention ----------------
// grid (S/64, B*H). 4 waves; wave w owns q rows q0+w*16..+15. KV tile = 64.
// K tile [64 key][64 d], V^T tile [64 d][64 key] in LDS (swizzled like GEMM).
// online softmax in f32 registers; P transposed via per-wave swizzled LDS.
__global__ __launch_bounds__(256) void attn64(
    const f16* __restrict__ qg, const f16* __restrict__ kg,
    const f16* __restrict__ vtg, f16* __restrict__ aout) {
  __shared__ char lds[24576];
  char* ldsK = lds;
  char* ldsV = lds + 8192;
  char* ldsP = lds + 16384;

  const int tid = threadIdx.x;
  const int l = tid & 63, w = tid >> 6;
  const int g = l >> 4, c = l & 15;
  const int bh = blockIdx.y;
  const int q0 = blockIdx.x * 64;
  const int qrow = q0 + w * 16 + c;  // A-frag row for this lane

  f16x8 qf[2];
#pragma unroll
  for (int kc = 0; kc < 2; ++kc)
    qf[kc] = *(const f16x8*)(qg + ((size_t)bh * SEQ + qrow) * DH + kc * 32 + g * 8);

  float m_run[4], l_run[4];
#pragma unroll
  for (int e = 0; e < 4; ++e) { m_run[e] = -1e30f; l_run[e] = 0.0f; }
  f32x4 o_acc[4] = {};

  const int srow = w * 8 + (l >> 3);
  const int schunk = (l & 7) ^ ((l >> 3) & 7);
  char* ldsPw = ldsP + w * 2048;

  for (int t = 0; t < 32; ++t) {
#pragma unroll
    for (int it = 0; it < 2; ++it) {
      int row = it * 32 + srow;
      gload_lds16(kg + ((size_t)bh * SEQ + t * 64 + row) * DH + schunk * 8,
                  ldsK + it * 4096 + w * 1024);
      gload_lds16(vtg + ((size_t)bh * DH + row) * SEQ + t * 64 + schunk * 8,
                  ldsV + it * 4096 + w * 1024);
    }
    __syncthreads();

    // S = Q.K^T (Q pre-scaled by 0.125)
    f32x4 sc[4] = {};
#pragma unroll
    for (int kc = 0; kc < 2; ++kc)
#pragma unroll
      for (int n = 0; n < 4; ++n) {
        int row = n * 16 + c;  // key row
        f16x8 kf = *(const f16x8*)(ldsK + row * 128 + (((kc * 4 + g) ^ (row & 7)) << 4));
        sc[n] = __builtin_amdgcn_mfma_f32_16x16x32_f16(qf[kc], kf, sc[n], 0, 0, 0);
      }

    // online softmax; lane owns rows g*4+e (replicated over 16 c-lanes)
    float al[4];
#pragma unroll
    for (int e = 0; e < 4; ++e) {
      float m = fmaxf(fmaxf(sc[0][e], sc[1][e]), fmaxf(sc[2][e], sc[3][e]));
#pragma unroll
      for (int off = 1; off < 16; off <<= 1) m = fmaxf(m, __shfl_xor(m, off));
      float mn = fmaxf(m_run[e], m);
      float a = __expf(m_run[e] - mn);
      float p0 = __expf(sc[0][e] - mn);
      float p1 = __expf(sc[1][e] - mn);
      float p2 = __expf(sc[2][e] - mn);
      float p3 = __expf(sc[3][e] - mn);
      sc[0][e] = p0; sc[1][e] = p1; sc[2][e] = p2; sc[3][e] = p3;
      float sum = p0 + p1 + p2 + p3;
#pragma unroll
      for (int off = 1; off < 16; off <<= 1) sum += __shfl_xor(sum, off);
      l_run[e] = l_run[e] * a + sum;
      m_run[e] = mn;
      al[e] = a;
    }
#pragma unroll
    for (int n = 0; n < 4; ++n)
#pragma unroll
      for (int e = 0; e < 4; ++e) o_acc[n][e] *= al[e];

    // P -> per-wave LDS [16 q][64 key] f16, swizzled (write C-layout, read A-layout)
#pragma unroll
    for (int n = 0; n < 4; ++n) {
      int col = n * 16 + c;
      int chunk = col >> 3;
#pragma unroll
      for (int e = 0; e < 4; ++e) {
        int row = g * 4 + e;
        *(f16*)(ldsPw + row * 128 + ((chunk ^ (row & 7)) << 4) + (col & 7) * 2) =
            (f16)sc[n][e];
      }
    }

    // O += P.V  (A = P rows=q, k=key; B = V keys x d via V^T rows=d)
#pragma unroll
    for (int kc = 0; kc < 2; ++kc) {
      f16x8 pf = *(const f16x8*)(ldsPw + c * 128 + (((kc * 4 + g) ^ (c & 7)) << 4));
#pragma unroll
      for (int n = 0; n < 4; ++n) {
        int vrow = n * 16 + c;  // d row in V^T
        f16x8 vf = *(const f16x8*)(ldsV + vrow * 128 + (((kc * 4 + g) ^ (vrow & 7)) << 4));
        o_acc[n] = __builtin_amdgcn_mfma_f32_16x16x32_f16(pf, vf, o_acc[n], 0, 0, 0);
      }
    }
    __syncthreads();
  }

  // write attn_out [B*S][D] f16 (merged heads) = GEMM-ready A
  const int b = bh >> 4, h = bh & 15;
#pragma unroll
  for (int n = 0; n < 4; ++n) {
    int d = n * 16 + c;
#pragma unroll
    for (int e = 0; e < 4; ++e) {
      int s = q0 + w * 16 + g * 4 + e;
      float val = o_acc[n][e] / l_run[e];
      aout[((size_t)(b * SEQ + s)) * DMODEL + h * DH + d] = (f16)val;
    }
  }
}

extern "C" void kernel_launch(void* const* d_in, const int* in_sizes, int n_in,
                              void* d_out, int out_size, void* d_ws, size_t ws_size,
                              hipStream_t stream) {
  const float* hq = (const float*)d_in[0];
  const float* hk = (const float*)d_in[1];
  const float* hv = (const float*)d_in[2];
  const float* Wq = (const float*)d_in[3];
  const float* bq = (const float*)d_in[4];
  const float* Wk = (const float*)d_in[5];
  const float* bk = (const float*)d_in[6];
  const float* Wv = (const float*)d_in[7];
  const float* bv = (const float*)d_in[8];
  const float* Wp = (const float*)d_in[9];
  const float* bp = (const float*)d_in[10];
  float* out = (float*)d_out;

  // workspace layout (64 MiB total)
  f16* xq  = (f16*)d_ws;
  f16* xk  = xq + 4194304;   // 4096*1024
  f16* xv  = xk + 4194304;
  f16* wqt = xv + 4194304;
  f16* wkt = wqt + 1048576;  // 1024*1024
  f16* wvt = wkt + 1048576;
  f16* wpt = wvt + 1048576;
  f16* qb  = wpt + 1048576;  // [BH][S][64]
  f16* kb  = qb + 4194304;
  f16* vtb = kb + 4194304;   // [BH][64][S]
  f16* ao  = vtb + 4194304;  // [B*S][D]

  cast_f16_3<<<dim3(2048, 1, 3), 256, 0, stream>>>(hq, hk, hv, xq, xk, xv);
  transw<<<dim3(16, 16, 4), 256, 0, stream>>>(Wq, Wk, Wv, Wp, wqt, wkt, wvt, wpt);
  gemm128<<<dim3(8, 32, 3), 256, 0, stream>>>(xq, xk, xv, ao, wqt, wkt, wvt, wpt,
                                              bq, bk, bv, bp, qb, kb, vtb, out, 0);
  attn64<<<dim3(32, 32), 256, 0, stream>>>(qb, kb, vtb, ao);
  gemm128<<<dim3(8, 32, 1), 256, 0, stream>>>(xq, xk, xv, ao, wqt, wkt, wvt, wpt,
                                              bq, bk, bv, bp, qb, kb, vtb, out, 3);
}

// Round 3
// 168.378 us; speedup vs baseline: 1.2253x; 1.2253x over previous
//
#include <hip/hip_runtime.h>
#include <stdint.h>

// SimpleGPT2Attention on MI355X (gfx950).
// B=2, S=2048, D=1024, H=16, dh=64. All inputs f32; output f32.
// Pipeline: cast->f16, transpose weights, QKV GEMM (f16 MFMA), flash attn, out GEMM.

typedef _Float16 f16;
typedef __attribute__((ext_vector_type(8))) _Float16 f16x8;
typedef __attribute__((ext_vector_type(4))) _Float16 f16x4;
typedef __attribute__((ext_vector_type(4))) float f32x4;

#define NB 2
#define SEQ 2048
#define DMODEL 1024
#define NH 16
#define DH 64

// Q projection scale: 1/sqrt(64) * log2(e)  (softmax done in exp2 domain)
#define QSCALE 0.1803368801111601f

// async global->LDS, 16B per lane, dst = wave-uniform base + lane*16 (HW rule)
__device__ __forceinline__ void gload_lds16(const void* g, void* l) {
  __builtin_amdgcn_global_load_lds(
      (const __attribute__((address_space(1))) unsigned int*)g,
      (__attribute__((address_space(3))) unsigned int*)l, 16, 0, 0);
}

// ---------------- cast f32 -> f16, 8 elems/thread ----------------
__global__ __launch_bounds__(256) void cast_f16_3(
    const float* __restrict__ s0, const float* __restrict__ s1,
    const float* __restrict__ s2, f16* __restrict__ d0, f16* __restrict__ d1,
    f16* __restrict__ d2) {
  const float* src = blockIdx.z == 0 ? s0 : (blockIdx.z == 1 ? s1 : s2);
  f16* dst = blockIdx.z == 0 ? d0 : (blockIdx.z == 1 ? d1 : d2);
  int i = (blockIdx.x * 256 + threadIdx.x) * 8;
  float4 a = *(const float4*)(src + i);
  float4 b = *(const float4*)(src + i + 4);
  f16x8 o;
  o[0] = (f16)a.x; o[1] = (f16)a.y; o[2] = (f16)a.z; o[3] = (f16)a.w;
  o[4] = (f16)b.x; o[5] = (f16)b.y; o[6] = (f16)b.z; o[7] = (f16)b.w;
  *(f16x8*)(dst + i) = o;
}

// ---------------- W [K][N] f32 -> WT [N][K] f16 ----------------
__global__ __launch_bounds__(256) void transw(
    const float* __restrict__ w0, const float* __restrict__ w1,
    const float* __restrict__ w2, const float* __restrict__ w3,
    f16* __restrict__ t0, f16* __restrict__ t1, f16* __restrict__ t2,
    f16* __restrict__ t3) {
  __shared__ float tile[64][65];
  const float* W; f16* T;
  switch (blockIdx.z) {
    case 0: W = w0; T = t0; break;
    case 1: W = w1; T = t1; break;
    case 2: W = w2; T = t2; break;
    default: W = w3; T = t3; break;
  }
  int r0 = blockIdx.y * 64, c0 = blockIdx.x * 64;
  for (int it = 0; it < 16; ++it) {
    int idx = it * 256 + threadIdx.x;
    int r = idx >> 6, c = idx & 63;
    tile[r][c] = W[(size_t)(r0 + r) * DMODEL + c0 + c];
  }
  __syncthreads();
  for (int it = 0; it < 16; ++it) {
    int idx = it * 256 + threadIdx.x;
    int r = idx >> 6, c = idx & 63;
    T[(size_t)(c0 + r) * DMODEL + r0 + c] = (f16)tile[c][r];
  }
}

// ---------------- GEMM: C[m][n] = A[m][:] . BT[n][:] + bias[n] ----------------
// 128x128 tile, BK=64, 4 waves (2x2 of 64x64), mfma_f32_16x16x32_f16.
// mode 0: Q out (scaled QSCALE, [BH,S,64] f16)  mode 1: K out ([BH,S,64] f16)
// mode 2: V out transposed ([BH,64,S] f16)      mode 3: f32 out (d_out)
__global__ __launch_bounds__(256) void gemm128(
    const f16* __restrict__ xq, const f16* __restrict__ xk,
    const f16* __restrict__ xv, const f16* __restrict__ ao,
    const f16* __restrict__ wqt, const f16* __restrict__ wkt,
    const f16* __restrict__ wvt, const f16* __restrict__ wpt,
    const float* __restrict__ bq, const float* __restrict__ bk,
    const float* __restrict__ bv, const float* __restrict__ bp,
    f16* __restrict__ qo, f16* __restrict__ ko, f16* __restrict__ vto,
    float* __restrict__ out, int mode_base) {
  __shared__ char lds[32768];
  char* ldsA = lds;
  char* ldsB = lds + 16384;

  int mode = mode_base + blockIdx.z;
  const f16* Am; const f16* Bt; const float* bias; float oscale = 1.0f;
  if (mode == 0)      { Am = xq; Bt = wqt; bias = bq; oscale = QSCALE; }
  else if (mode == 1) { Am = xk; Bt = wkt; bias = bk; }
  else if (mode == 2) { Am = xv; Bt = wvt; bias = bv; }
  else                { Am = ao; Bt = wpt; bias = bp; }

  const int tid = threadIdx.x;
  const int l = tid & 63, w = tid >> 6;
  const int g = l >> 4, c = l & 15;
  const int wr = w >> 1, wc = w & 1;
  const int m0 = blockIdx.y * 128, n0 = blockIdx.x * 128;

  const int srow = w * 8 + (l >> 3);
  const int schunk = (l & 7) ^ ((l >> 3) & 7);

  f32x4 acc[4][4] = {};

  for (int k0 = 0; k0 < DMODEL; k0 += 64) {
#pragma unroll
    for (int it = 0; it < 4; ++it) {
      int row = it * 32 + srow;
      gload_lds16(Am + (size_t)(m0 + row) * DMODEL + k0 + schunk * 8,
                  ldsA + it * 4096 + w * 1024);
    }
#pragma unroll
    for (int it = 0; it < 4; ++it) {
      int row = it * 32 + srow;
      gload_lds16(Bt + (size_t)(n0 + row) * DMODEL + k0 + schunk * 8,
                  ldsB + it * 4096 + w * 1024);
    }
    __syncthreads();
    f16x8 af[2][4], bf[2][4];
#pragma unroll
    for (int kc = 0; kc < 2; ++kc)
#pragma unroll
      for (int i = 0; i < 4; ++i) {
        int row = wr * 64 + i * 16 + c;
        af[kc][i] = *(const f16x8*)(ldsA + row * 128 + (((kc * 4 + g) ^ (row & 7)) << 4));
        int rowb = wc * 64 + i * 16 + c;
        bf[kc][i] = *(const f16x8*)(ldsB + rowb * 128 + (((kc * 4 + g) ^ (rowb & 7)) << 4));
      }
#pragma unroll
    for (int kc = 0; kc < 2; ++kc)
#pragma unroll
      for (int i = 0; i < 4; ++i)
#pragma unroll
        for (int j = 0; j < 4; ++j)
          acc[i][j] = __builtin_amdgcn_mfma_f32_16x16x32_f16(af[kc][i], bf[kc][j],
                                                             acc[i][j], 0, 0, 0);
    __syncthreads();
  }

  // epilogue: lane holds C[(l>>4)*4 + e][l&15] per 16x16 frag (m89 layout)
#pragma unroll
  for (int i = 0; i < 4; ++i) {
#pragma unroll
    for (int j = 0; j < 4; ++j) {
      int grb = m0 + wr * 64 + i * 16 + g * 4;
      int gc = n0 + wc * 64 + j * 16 + c;
      float bval = bias[gc];
      if (mode == 3) {
#pragma unroll
        for (int e = 0; e < 4; ++e)
          out[(size_t)(grb + e) * DMODEL + gc] = acc[i][j][e] + bval;
      } else if (mode == 2) {  // V^T: [BH][dh][S]
        int b = grb >> 11, s = grb & 2047, h = gc >> 6, d = gc & 63;
        f16x4 pk;
#pragma unroll
        for (int e = 0; e < 4; ++e) pk[e] = (f16)(acc[i][j][e] + bval);
        *(f16x4*)(vto + ((size_t)((b * NH + h) * DH + d)) * SEQ + s) = pk;
      } else {  // Q/K: [BH][S][dh]
        f16* dst = (mode == 0) ? qo : ko;
        int b = grb >> 11, s = grb & 2047, h = gc >> 6, d = gc & 63;
#pragma unroll
        for (int e = 0; e < 4; ++e)
          dst[(((size_t)(b * NH + h) * SEQ) + (s + e)) * DH + d] =
              (f16)((acc[i][j][e] + bval) * oscale);
      }
    }
  }
}

// ---------------- flash attention (swapped QK^T, 32 q-rows/wave) ----------------
// grid (S/128, B*H), 4 waves. Wave w owns q rows [q0+w*32, +32) as 2 frags of 16.
// K tile [64 key][64 d] and V^T tile [64 d][64 key] double-buffered in LDS.
// Swapped mfma(K,Q) -> lane owns one q column; softmax nearly in-register.
// P repacked to B-frags via cvt_pkrtz + per-wave LDS b64/b128 round trip.
__global__ __launch_bounds__(256) void attn64(
    const f16* __restrict__ qg, const f16* __restrict__ kg,
    const f16* __restrict__ vtg, f16* __restrict__ aout) {
  __shared__ char lds[40960];  // 2 x (K 8KB + V 8KB) dbuf + 4 x 2KB P

  const int tid = threadIdx.x;
  const int l = tid & 63, w = tid >> 6;
  const int g = l >> 4, c = l & 15;
  const int bh = blockIdx.y;
  const int q0 = blockIdx.x * 128 + w * 32;

  // Q as B-operand frags: lane holds Q[q = q0+qf2*16+c][d = kc*32+g*8 .. +8]
  f16x8 qf[2][2];
#pragma unroll
  for (int qf2 = 0; qf2 < 2; ++qf2)
#pragma unroll
    for (int kc = 0; kc < 2; ++kc)
      qf[qf2][kc] = *(const f16x8*)(
          qg + ((size_t)bh * SEQ + q0 + qf2 * 16 + c) * DH + kc * 32 + g * 8);

  float m_run[2] = {-1e30f, -1e30f}, l_run[2] = {0.0f, 0.0f};
  f32x4 o_acc[2][4] = {};  // lane holds O^T[d = dn*16+g*4+e][q=c]

  const int srow = w * 8 + (l >> 3);
  const int schunk = (l & 7) ^ ((l >> 3) & 7);
  char* ldsP = lds + 32768 + w * 2048;  // per-wave P buffer [16 q][64 key] f16 swz

  auto stage = [&](int buf, int t) {
    char* base = lds + buf * 16384;
#pragma unroll
    for (int it = 0; it < 2; ++it) {
      int row = it * 32 + srow;
      gload_lds16(kg + ((size_t)bh * SEQ + t * 64 + row) * DH + schunk * 8,
                  base + it * 4096 + w * 1024);
      gload_lds16(vtg + ((size_t)bh * DH + row) * SEQ + t * 64 + schunk * 8,
                  base + 8192 + it * 4096 + w * 1024);
    }
  };

  stage(0, 0);
  __syncthreads();

  for (int t = 0; t < 32; ++t) {
    int cur = t & 1;
    if (t + 1 < 32) stage(cur ^ 1, t + 1);  // overlaps with compute below

    const char* ldsK = lds + cur * 16384;
    const char* ldsV = ldsK + 8192;

    // S^T = K.Q : st[qf2][n], value(e) = S[key = n*16+g*4+e][q = c]
    f32x4 st[2][4] = {};
#pragma unroll
    for (int kc = 0; kc < 2; ++kc)
#pragma unroll
      for (int n = 0; n < 4; ++n) {
        int row = n * 16 + c;
        f16x8 kf = *(const f16x8*)(ldsK + row * 128 + (((kc * 4 + g) ^ (row & 7)) << 4));
        st[0][n] = __builtin_amdgcn_mfma_f32_16x16x32_f16(kf, qf[0][kc], st[0][n], 0, 0, 0);
        st[1][n] = __builtin_amdgcn_mfma_f32_16x16x32_f16(kf, qf[1][kc], st[1][n], 0, 0, 0);
      }

    f16x8 pb[2][2];  // B-frags of P: pb[qf2][kc2][j] = P[q=c][key=kc2*32+g*8+j]
#pragma unroll
    for (int qf2 = 0; qf2 < 2; ++qf2) {
      // row max over 64 keys for q=c: 15 in-lane + 2 shfl (across g groups)
      float pm = st[qf2][0][0];
#pragma unroll
      for (int n = 0; n < 4; ++n)
#pragma unroll
        for (int e = 0; e < 4; ++e) pm = fmaxf(pm, st[qf2][n][e]);
      pm = fmaxf(pm, __shfl_xor(pm, 16));
      pm = fmaxf(pm, __shfl_xor(pm, 32));

      float mr = m_run[qf2];
      if (!__all(pm <= mr + 11.0f)) {  // defer-max (exp2 domain)
        float mn = fmaxf(mr, pm);
        float a = exp2f(mr - mn);
        l_run[qf2] *= a;
#pragma unroll
        for (int dn = 0; dn < 4; ++dn)
#pragma unroll
          for (int e = 0; e < 4; ++e) o_acc[qf2][dn][e] *= a;
        m_run[qf2] = mn;
        mr = mn;
      }

      float p[4][4];
      float sum = 0.0f;
#pragma unroll
      for (int n = 0; n < 4; ++n)
#pragma unroll
        for (int e = 0; e < 4; ++e) {
          p[n][e] = exp2f(st[qf2][n][e] - mr);
          sum += p[n][e];
        }
      sum += __shfl_xor(sum, 16);
      sum += __shfl_xor(sum, 32);
      l_run[qf2] += sum;

      // pack P -> f16 pairs, per-wave LDS round trip to transpose into B-frags.
      // write: keys n*16+g*4+{0..3} for q=c -> row c, chunk 2n+(g>>1), off (g&1)*8
#pragma unroll
      for (int n = 0; n < 4; ++n) {
        uint2 wv;
        wv.x = __builtin_bit_cast(unsigned,
                                  __builtin_amdgcn_cvt_pkrtz(p[n][0], p[n][1]));
        wv.y = __builtin_bit_cast(unsigned,
                                  __builtin_amdgcn_cvt_pkrtz(p[n][2], p[n][3]));
        *(uint2*)(ldsP + c * 128 + (((2 * n + (g >> 1)) ^ (c & 7)) << 4) +
                  (g & 1) * 8) = wv;
      }
#pragma unroll
      for (int kc2 = 0; kc2 < 2; ++kc2)
        pb[qf2][kc2] =
            *(const f16x8*)(ldsP + c * 128 + (((kc2 * 4 + g) ^ (c & 7)) << 4));
    }

    // O^T += V^T . P^T : o_acc[qf2][dn] with A = V^T frag, B = P frag
#pragma unroll
    for (int kc2 = 0; kc2 < 2; ++kc2)
#pragma unroll
      for (int dn = 0; dn < 4; ++dn) {
        int row = dn * 16 + c;
        f16x8 vf = *(const f16x8*)(ldsV + row * 128 + (((kc2 * 4 + g) ^ (row & 7)) << 4));
        o_acc[0][dn] = __builtin_amdgcn_mfma_f32_16x16x32_f16(vf, pb[0][kc2], o_acc[0][dn], 0, 0, 0);
        o_acc[1][dn] = __builtin_amdgcn_mfma_f32_16x16x32_f16(vf, pb[1][kc2], o_acc[1][dn], 0, 0, 0);
      }
    __syncthreads();
  }

  // write attn_out [B*S][D] f16 (merged heads); lane has d = dn*16+g*4+{0..3}
  const int b = bh >> 4, h = bh & 15;
#pragma unroll
  for (int qf2 = 0; qf2 < 2; ++qf2) {
    float inv = 1.0f / l_run[qf2];
    int s = q0 + qf2 * 16 + c;
#pragma unroll
    for (int dn = 0; dn < 4; ++dn) {
      f16x4 pk;
#pragma unroll
      for (int e = 0; e < 4; ++e) pk[e] = (f16)(o_acc[qf2][dn][e] * inv);
      *(f16x4*)(aout + ((size_t)(b * SEQ + s)) * DMODEL + h * DH + dn * 16 + g * 4) = pk;
    }
  }
}

extern "C" void kernel_launch(void* const* d_in, const int* in_sizes, int n_in,
                              void* d_out, int out_size, void* d_ws, size_t ws_size,
                              hipStream_t stream) {
  const float* hq = (const float*)d_in[0];
  const float* hk = (const float*)d_in[1];
  const float* hv = (const float*)d_in[2];
  const float* Wq = (const float*)d_in[3];
  const float* bq = (const float*)d_in[4];
  const float* Wk = (const float*)d_in[5];
  const float* bk = (const float*)d_in[6];
  const float* Wv = (const float*)d_in[7];
  const float* bv = (const float*)d_in[8];
  const float* Wp = (const float*)d_in[9];
  const float* bp = (const float*)d_in[10];
  float* out = (float*)d_out;

  // workspace layout (64 MiB total)
  f16* xq  = (f16*)d_ws;
  f16* xk  = xq + 4194304;   // 4096*1024
  f16* xv  = xk + 4194304;
  f16* wqt = xv + 4194304;
  f16* wkt = wqt + 1048576;  // 1024*1024
  f16* wvt = wkt + 1048576;
  f16* wpt = wvt + 1048576;
  f16* qb  = wpt + 1048576;  // [BH][S][64]
  f16* kb  = qb + 4194304;
  f16* vtb = kb + 4194304;   // [BH][64][S]
  f16* ao  = vtb + 4194304;  // [B*S][D]

  cast_f16_3<<<dim3(2048, 1, 3), 256, 0, stream>>>(hq, hk, hv, xq, xk, xv);
  transw<<<dim3(16, 16, 4), 256, 0, stream>>>(Wq, Wk, Wv, Wp, wqt, wkt, wvt, wpt);
  gemm128<<<dim3(8, 32, 3), 256, 0, stream>>>(xq, xk, xv, ao, wqt, wkt, wvt, wpt,
                                              bq, bk, bv, bp, qb, kb, vtb, out, 0);
  attn64<<<dim3(16, 32), 256, 0, stream>>>(qb, kb, vtb, ao);
  gemm128<<<dim3(8, 32, 1), 256, 0, stream>>>(xq, xk, xv, ao, wqt, wkt, wvt, wpt,
                                              bq, bk, bv, bp, qb, kb, vtb, out, 3);
}